// Round 2
// baseline (2715.602 us; speedup 1.0000x reference)
//
#include <hip/hip_runtime.h>
#include <math.h>

#define T_SEQ 2048
#define C_DIM 1024
#define NHEAD 16
#define HDIM 64
#define M_ROWS 4096   // B*T
#define N_QKV 3072    // 3*C
#define KCH 64        // key chunk staged in LDS

// ---------------- abs-mean scale (deterministic 2-stage reduction) ----------
__global__ __launch_bounds__(256) void abs_partial_k(const float* __restrict__ w,
                                                     int n, float* __restrict__ part) {
  __shared__ float red[256];
  float s = 0.f;
  for (int i = blockIdx.x * 256 + threadIdx.x; i < n; i += 256 * 256)
    s += fabsf(w[i]);
  red[threadIdx.x] = s;
  __syncthreads();
  for (int st = 128; st > 0; st >>= 1) {
    if ((int)threadIdx.x < st) red[threadIdx.x] += red[threadIdx.x + st];
    __syncthreads();
  }
  if (threadIdx.x == 0) part[blockIdx.x] = red[0];
}

__global__ __launch_bounds__(256) void finalize_scales_k(const float* __restrict__ part,
                                                         float* __restrict__ scales) {
  __shared__ float red[256];
  red[threadIdx.x] = part[blockIdx.x * 256 + threadIdx.x];
  __syncthreads();
  for (int st = 128; st > 0; st >>= 1) {
    if ((int)threadIdx.x < st) red[threadIdx.x] += red[threadIdx.x + st];
    __syncthreads();
  }
  if (threadIdx.x == 0) {
    float n = (blockIdx.x == 0) ? (float)(N_QKV * C_DIM) : (float)(C_DIM * C_DIM);
    scales[blockIdx.x] = fmaxf(red[0] / n, 1e-8f);
  }
}

// ---------------- ternarize: clip(round(w/scale), -1, 1) --------------------
__global__ __launch_bounds__(256) void ternarize_k(const float* __restrict__ w,
                                                   float* __restrict__ wt, int n,
                                                   const float* __restrict__ scales,
                                                   int which) {
  int i = blockIdx.x * 256 + threadIdx.x;
  if (i < n) {
    float s = scales[which];
    float t = rintf(w[i] / s);           // round-half-even matches jnp.round
    wt[i] = fminf(1.f, fmaxf(-1.f, t));
  }
}

// ---------------- fp32 GEMM: C[m][n] = sum_k A[m][k] * Bw[n][k] -------------
__global__ __launch_bounds__(256, 2) void gemm_nt(const float* __restrict__ A,
                                                  const float* __restrict__ Bw,
                                                  float* __restrict__ Cout,
                                                  int Nd, int Kd) {
  __shared__ __align__(16) float As[16][64];
  __shared__ __align__(16) float Bs[16][64];
  const int bm = blockIdx.y * 64;
  const int bn = blockIdx.x * 64;
  const int tid = threadIdx.x;
  const int tm = tid >> 4, tn = tid & 15;
  const int lr = tid >> 2;
  const int lk = (tid & 3) << 2;
  const float* Ap = A + (size_t)(bm + lr) * Kd + lk;
  const float* Bp = Bw + (size_t)(bn + lr) * Kd + lk;
  float acc[4][4] = {};
  for (int k0 = 0; k0 < Kd; k0 += 16) {
    const float4 av = *(const float4*)(Ap + k0);
    const float4 bv = *(const float4*)(Bp + k0);
    __syncthreads();
    As[lk + 0][lr] = av.x; As[lk + 1][lr] = av.y;
    As[lk + 2][lr] = av.z; As[lk + 3][lr] = av.w;
    Bs[lk + 0][lr] = bv.x; Bs[lk + 1][lr] = bv.y;
    Bs[lk + 2][lr] = bv.z; Bs[lk + 3][lr] = bv.w;
    __syncthreads();
#pragma unroll
    for (int k = 0; k < 16; ++k) {
      const float4 a = *(const float4*)(&As[k][tm << 2]);
      const float4 b = *(const float4*)(&Bs[k][tn << 2]);
      float a4[4] = {a.x, a.y, a.z, a.w};
      float b4[4] = {b.x, b.y, b.z, b.w};
#pragma unroll
      for (int i = 0; i < 4; ++i)
#pragma unroll
        for (int j = 0; j < 4; ++j)
          acc[i][j] = fmaf(a4[i], b4[j], acc[i][j]);
    }
  }
#pragma unroll
  for (int i = 0; i < 4; ++i) {
    float4 o = make_float4(acc[i][0], acc[i][1], acc[i][2], acc[i][3]);
    *(float4*)(Cout + (size_t)(bm + (tm << 2) + i) * Nd + bn + (tn << 2)) = o;
  }
}

// ---------------- flash attention, fp32, 4-way key-sliced -------------------
// Block: 256 threads = 64 queries x 4 key-slices. Grid: b*h*(T/64) = 1024.
// Lane group (4 consecutive lanes) shares one query; each lane holds private
// online-softmax state over its key subset; shfl-combine at the end.
__global__ __launch_bounds__(256, 3) void attn4_k(const float* __restrict__ qkv,
                                                  float* __restrict__ aout) {
  const int tid = threadIdx.x;
  const int qt = blockIdx.x & 31;          // fastest-varying: balances CU load
  const int h  = (blockIdx.x >> 5) & 15;
  const int b  = blockIdx.x >> 9;
  const int qq = tid >> 2;                 // query within tile, 0..63
  const int sl = tid & 3;                  // key slice 0..3
  const int qi = (qt << 6) + qq;
  const float* base = qkv + (size_t)b * T_SEQ * N_QKV;
  const float* qrow = base + (size_t)qi * N_QKV + (h << 6);

  float q[64], acc[64];
#pragma unroll
  for (int i = 0; i < 16; ++i) {
    float4 v4 = *(const float4*)(qrow + (i << 2));
    q[i * 4 + 0] = v4.x * 0.125f;          // fold 1/sqrt(64)
    q[i * 4 + 1] = v4.y * 0.125f;
    q[i * 4 + 2] = v4.z * 0.125f;
    q[i * 4 + 3] = v4.w * 0.125f;
  }
#pragma unroll
  for (int d = 0; d < 64; ++d) acc[d] = 0.f;
  float m = -1e30f, l = 0.f;               // -1e30 (finite): no NaN on all-masked

  __shared__ __align__(16) float ks[KCH][64];
  __shared__ __align__(16) float vs[KCH][64];

  const int kend = (qt << 6) + 64;
  for (int k0 = 0; k0 < kend; k0 += KCH) {
    __syncthreads();
#pragma unroll 2
    for (int i = 0; i < 4; ++i) {
      int idx = (i << 8) + tid;            // 0..1023 float4 granules
      int kr = idx >> 4, g = (idx & 15) << 2;
      const float* kp = base + (size_t)(k0 + kr) * N_QKV + C_DIM + (h << 6) + g;
      *(float4*)(&ks[kr][g]) = *(const float4*)(kp);
      *(float4*)(&vs[kr][g]) = *(const float4*)(kp + C_DIM);
    }
    __syncthreads();

    const int kb = sl << 4;                // my 16 keys: rows kb..kb+15
    const int kglo = k0 + kb;
#pragma unroll 1
    for (int jj = 0; jj < 16; jj += 4) {
      const float* kr0 = ks[kb + jj + 0];
      const float* kr1 = ks[kb + jj + 1];
      const float* kr2 = ks[kb + jj + 2];
      const float* kr3 = ks[kb + jj + 3];
      float s0 = 0.f, s1 = 0.f, s2 = 0.f, s3 = 0.f;
#pragma unroll
      for (int g = 0; g < 16; ++g) {
        const float4 a0 = *(const float4*)(kr0 + (g << 2));
        const float4 a1 = *(const float4*)(kr1 + (g << 2));
        const float4 a2 = *(const float4*)(kr2 + (g << 2));
        const float4 a3 = *(const float4*)(kr3 + (g << 2));
        s0 = fmaf(q[g*4+0], a0.x, s0); s0 = fmaf(q[g*4+1], a0.y, s0);
        s0 = fmaf(q[g*4+2], a0.z, s0); s0 = fmaf(q[g*4+3], a0.w, s0);
        s1 = fmaf(q[g*4+0], a1.x, s1); s1 = fmaf(q[g*4+1], a1.y, s1);
        s1 = fmaf(q[g*4+2], a1.z, s1); s1 = fmaf(q[g*4+3], a1.w, s1);
        s2 = fmaf(q[g*4+0], a2.x, s2); s2 = fmaf(q[g*4+1], a2.y, s2);
        s2 = fmaf(q[g*4+2], a2.z, s2); s2 = fmaf(q[g*4+3], a2.w, s2);
        s3 = fmaf(q[g*4+0], a3.x, s3); s3 = fmaf(q[g*4+1], a3.y, s3);
        s3 = fmaf(q[g*4+2], a3.z, s3); s3 = fmaf(q[g*4+3], a3.w, s3);
      }
      s0 = (kglo + jj + 0 <= qi) ? s0 : -1e30f;
      s1 = (kglo + jj + 1 <= qi) ? s1 : -1e30f;
      s2 = (kglo + jj + 2 <= qi) ? s2 : -1e30f;
      s3 = (kglo + jj + 3 <= qi) ? s3 : -1e30f;
      const float mc = fmaxf(fmaxf(s0, s1), fmaxf(s2, s3));
      if (mc > m) {
        const float r = __expf(m - mc);
        l *= r;
#pragma unroll
        for (int d = 0; d < 64; ++d) acc[d] *= r;
        m = mc;
      }
      const float p0 = __expf(s0 - m), p1 = __expf(s1 - m);
      const float p2 = __expf(s2 - m), p3 = __expf(s3 - m);
      l += (p0 + p1) + (p2 + p3);
      const float* vr0 = vs[kb + jj + 0];
      const float* vr1 = vs[kb + jj + 1];
      const float* vr2 = vs[kb + jj + 2];
      const float* vr3 = vs[kb + jj + 3];
#pragma unroll
      for (int g = 0; g < 16; ++g) {
        const float4 v0 = *(const float4*)(vr0 + (g << 2));
        const float4 v1 = *(const float4*)(vr1 + (g << 2));
        const float4 v2 = *(const float4*)(vr2 + (g << 2));
        const float4 v3 = *(const float4*)(vr3 + (g << 2));
        acc[g*4+0] = fmaf(p0, v0.x, fmaf(p1, v1.x, fmaf(p2, v2.x, fmaf(p3, v3.x, acc[g*4+0]))));
        acc[g*4+1] = fmaf(p0, v0.y, fmaf(p1, v1.y, fmaf(p2, v2.y, fmaf(p3, v3.y, acc[g*4+1]))));
        acc[g*4+2] = fmaf(p0, v0.z, fmaf(p1, v1.z, fmaf(p2, v2.z, fmaf(p3, v3.z, acc[g*4+2]))));
        acc[g*4+3] = fmaf(p0, v0.w, fmaf(p1, v1.w, fmaf(p2, v2.w, fmaf(p3, v3.w, acc[g*4+3]))));
      }
    }
  }

  // ---- combine the 4 slice-partials (lanes sl=0..3 of each 4-lane group) ----
  const float mA = fmaxf(m, __shfl_xor(m, 1));
  const float ms = fmaxf(mA, __shfl_xor(mA, 2));
  const float e = __expf(m - ms);          // 0 for an all-masked slice
  float lw = l * e;
  lw += __shfl_xor(lw, 1);
  lw += __shfl_xor(lw, 2);
#pragma unroll
  for (int d = 0; d < 64; ++d) acc[d] *= e;
  // recursive halving over dims; all register indices compile-time
  float h32[32];
#pragma unroll
  for (int d = 0; d < 32; ++d) {
    const float tl = __shfl_xor(acc[d], 1);
    const float th = __shfl_xor(acc[d + 32], 1);
    h32[d] = (sl & 1) ? (acc[d + 32] + th) : (acc[d] + tl);
  }
  float h16[16];
#pragma unroll
  for (int d = 0; d < 16; ++d) {
    const float tl = __shfl_xor(h32[d], 2);
    const float th = __shfl_xor(h32[d + 16], 2);
    h16[d] = (sl & 2) ? (h32[d + 16] + th) : (h32[d] + tl);
  }
  const float inv = 1.f / lw;
  const int doff = ((sl & 1) << 5) | ((sl & 2) << 3);   // 0,32,16,48
  float* op = aout + (size_t)(b * T_SEQ + qi) * C_DIM + (h << 6) + doff;
#pragma unroll
  for (int i = 0; i < 4; ++i) {
    float4 o = make_float4(h16[i*4+0] * inv, h16[i*4+1] * inv,
                           h16[i*4+2] * inv, h16[i*4+3] * inv);
    *(float4*)(op + (i << 2)) = o;
  }
}

// ---------------- launch ----------------------------------------------------
extern "C" void kernel_launch(void* const* d_in, const int* in_sizes, int n_in,
                              void* d_out, int out_size, void* d_ws, size_t ws_size,
                              hipStream_t stream) {
  const float* x      = (const float*)d_in[0];   // [4096][1024]
  const float* w_qkv  = (const float*)d_in[1];   // [3072][1024]
  const float* w_out  = (const float*)d_in[2];   // [1024][1024]
  float* out = (float*)d_out;                    // [4096][1024]
  float* ws = (float*)d_ws;

  float* wt_qkv = ws;
  float* wt_out = wt_qkv + (size_t)N_QKV * C_DIM;
  float* qkv    = wt_out + (size_t)C_DIM * C_DIM;
  float* aout   = qkv + (size_t)M_ROWS * N_QKV;
  float* part   = aout + (size_t)M_ROWS * C_DIM;
  float* scales = part + 512;

  hipLaunchKernelGGL(abs_partial_k, dim3(256), dim3(256), 0, stream,
                     w_qkv, N_QKV * C_DIM, part);
  hipLaunchKernelGGL(abs_partial_k, dim3(256), dim3(256), 0, stream,
                     w_out, C_DIM * C_DIM, part + 256);
  hipLaunchKernelGGL(finalize_scales_k, dim3(2), dim3(256), 0, stream, part, scales);

  hipLaunchKernelGGL(ternarize_k, dim3((N_QKV * C_DIM) / 256), dim3(256), 0, stream,
                     w_qkv, wt_qkv, N_QKV * C_DIM, scales, 0);
  hipLaunchKernelGGL(ternarize_k, dim3((C_DIM * C_DIM) / 256), dim3(256), 0, stream,
                     w_out, wt_out, C_DIM * C_DIM, scales, 1);

  hipLaunchKernelGGL(gemm_nt, dim3(N_QKV / 64, M_ROWS / 64), dim3(256), 0, stream,
                     x, wt_qkv, qkv, N_QKV, C_DIM);

  hipLaunchKernelGGL(attn4_k, dim3(1024), dim3(256), 0, stream, qkv, aout);

  hipLaunchKernelGGL(gemm_nt, dim3(C_DIM / 64, M_ROWS / 64), dim3(256), 0, stream,
                     aout, wt_out, out, C_DIM, C_DIM);
}

// Round 3
// 632.786 us; speedup vs baseline: 4.2915x; 4.2915x over previous
//
#include <hip/hip_runtime.h>
#include <math.h>

#define T_SEQ 2048
#define C_DIM 1024
#define NHEAD 16
#define HDIM 64
#define M_ROWS 4096   // B*T
#define N_QKV 3072    // 3*C

typedef __attribute__((ext_vector_type(8))) short short8;   // 8 bf16 (4 VGPR)
typedef __attribute__((ext_vector_type(4))) float f32x4;    // MFMA C/D

__device__ inline unsigned short f2bf(float x) {            // RNE f32->bf16
  union { float f; unsigned u; } v; v.f = x;
  unsigned r = v.u + 0x7FFF + ((v.u >> 16) & 1);
  return (unsigned short)(r >> 16);
}
__device__ inline float bf2f(unsigned short h) {
  union { unsigned u; float f; } v; v.u = ((unsigned)h) << 16; return v.f;
}

// ---------------- abs-mean scale (deterministic 2-stage reduction) ----------
__global__ __launch_bounds__(256) void abs_partial_k(const float* __restrict__ w,
                                                     int n, float* __restrict__ part) {
  __shared__ float red[256];
  float s = 0.f;
  for (int i = blockIdx.x * 256 + threadIdx.x; i < n; i += 256 * 256)
    s += fabsf(w[i]);
  red[threadIdx.x] = s;
  __syncthreads();
  for (int st = 128; st > 0; st >>= 1) {
    if ((int)threadIdx.x < st) red[threadIdx.x] += red[threadIdx.x + st];
    __syncthreads();
  }
  if (threadIdx.x == 0) part[blockIdx.x] = red[0];
}

__global__ __launch_bounds__(256) void finalize_scales_k(const float* __restrict__ part,
                                                         float* __restrict__ scales) {
  __shared__ float red[256];
  red[threadIdx.x] = part[blockIdx.x * 256 + threadIdx.x];
  __syncthreads();
  for (int st = 128; st > 0; st >>= 1) {
    if ((int)threadIdx.x < st) red[threadIdx.x] += red[threadIdx.x + st];
    __syncthreads();
  }
  if (threadIdx.x == 0) {
    float n = (blockIdx.x == 0) ? (float)(N_QKV * C_DIM) : (float)(C_DIM * C_DIM);
    scales[blockIdx.x] = fmaxf(red[0] / n, 1e-8f);
  }
}

// ---------------- ternarize: clip(round(w/scale), -1, 1) --------------------
__global__ __launch_bounds__(256) void ternarize_k(const float* __restrict__ w,
                                                   float* __restrict__ wt, int n,
                                                   const float* __restrict__ scales,
                                                   int which) {
  int i = blockIdx.x * 256 + threadIdx.x;
  if (i < n) {
    float s = scales[which];
    float t = rintf(w[i] / s);           // round-half-even matches jnp.round
    wt[i] = fminf(1.f, fmaxf(-1.f, t));
  }
}

// ---------------- fp32 GEMM: C[m][n] = sum_k A[m][k] * Bw[n][k] -------------
__global__ __launch_bounds__(256, 2) void gemm_nt(const float* __restrict__ A,
                                                  const float* __restrict__ Bw,
                                                  float* __restrict__ Cout,
                                                  int Nd, int Kd) {
  __shared__ __align__(16) float As[16][64];
  __shared__ __align__(16) float Bs[16][64];
  const int bm = blockIdx.y * 64;
  const int bn = blockIdx.x * 64;
  const int tid = threadIdx.x;
  const int tm = tid >> 4, tn = tid & 15;
  const int lr = tid >> 2;
  const int lk = (tid & 3) << 2;
  const float* Ap = A + (size_t)(bm + lr) * Kd + lk;
  const float* Bp = Bw + (size_t)(bn + lr) * Kd + lk;
  float acc[4][4] = {};
  for (int k0 = 0; k0 < Kd; k0 += 16) {
    const float4 av = *(const float4*)(Ap + k0);
    const float4 bv = *(const float4*)(Bp + k0);
    __syncthreads();
    As[lk + 0][lr] = av.x; As[lk + 1][lr] = av.y;
    As[lk + 2][lr] = av.z; As[lk + 3][lr] = av.w;
    Bs[lk + 0][lr] = bv.x; Bs[lk + 1][lr] = bv.y;
    Bs[lk + 2][lr] = bv.z; Bs[lk + 3][lr] = bv.w;
    __syncthreads();
#pragma unroll
    for (int k = 0; k < 16; ++k) {
      const float4 a = *(const float4*)(&As[k][tm << 2]);
      const float4 b = *(const float4*)(&Bs[k][tn << 2]);
      float a4[4] = {a.x, a.y, a.z, a.w};
      float b4[4] = {b.x, b.y, b.z, b.w};
#pragma unroll
      for (int i = 0; i < 4; ++i)
#pragma unroll
        for (int j = 0; j < 4; ++j)
          acc[i][j] = fmaf(a4[i], b4[j], acc[i][j]);
    }
  }
#pragma unroll
  for (int i = 0; i < 4; ++i) {
    float4 o = make_float4(acc[i][0], acc[i][1], acc[i][2], acc[i][3]);
    *(float4*)(Cout + (size_t)(bm + (tm << 2) + i) * Nd + bn + (tn << 2)) = o;
  }
}

// ---------------- MFMA flash attention ---------------------------------------
// Block: 256 thr = 4 waves; Q-tile 64 queries (wave w owns rows w*16..+15).
// K-chunks of 64 staged in LDS as bf16 hi/lo (XOR-swizzled); V staged transposed.
// QK^T = 3 split MFMA passes (fp32-accurate scores); softmax fp32 on VALU;
// P->bf16 via per-wave LDS; PV plain bf16 MFMA.
__global__ __launch_bounds__(256, 2) void attn_mfma_k(const float* __restrict__ qkv,
                                                      float* __restrict__ aout) {
  __shared__ __align__(16) char smem[32768];
  char* const khp = smem;            // K hi  [64 key][64 dim] bf16, swizzled
  char* const klp = smem + 8192;     // K lo
  char* const vTp = smem + 16384;    // V^T  [64 dim][64 key] bf16, swizzled
  char* const pp  = smem + 24576;    // P    per-wave [16 q][64 key] bf16

  const int tid  = threadIdx.x;
  const int lane = tid & 63;
  const int w    = tid >> 6;
  const int lg   = lane >> 4;        // 0..3
  const int lr   = lane & 15;        // 0..15

  // XCD-aware decode: same (b,h) -> same XCD so its 2MB K/V slice stays L2-hot
  const int bx = blockIdx.x;
  const int qt = (bx >> 3) & 31;
  const int gg = ((bx >> 8) << 3) | (bx & 7);   // 0..31 = (b,h)
  const int h  = gg & 15, b = gg >> 4;

  const float* base = qkv + (size_t)b * T_SEQ * N_QKV;

  // Q fragments in registers: scaled by 1/8 (exact pow2), hi/lo bf16 split
  short8 qh[2], ql[2];
  {
    const float* qrow = base + (size_t)(qt * 64 + w * 16 + lr) * N_QKV + (h << 6);
#pragma unroll
    for (int s = 0; s < 2; ++s) {
      const float4 a0 = *(const float4*)(qrow + s * 32 + lg * 8);
      const float4 a1 = *(const float4*)(qrow + s * 32 + lg * 8 + 4);
      const float xv[8] = {a0.x, a0.y, a0.z, a0.w, a1.x, a1.y, a1.z, a1.w};
#pragma unroll
      for (int j = 0; j < 8; ++j) {
        const float xs = xv[j] * 0.125f;
        const unsigned short hs = f2bf(xs);
        qh[s][j] = (short)hs;
        ql[s][j] = (short)f2bf(xs - bf2f(hs));
      }
    }
  }

  f32x4 O[4] = {{0.f,0.f,0.f,0.f},{0.f,0.f,0.f,0.f},{0.f,0.f,0.f,0.f},{0.f,0.f,0.f,0.f}};
  float m[4]    = {-1e30f, -1e30f, -1e30f, -1e30f};
  float lsum[4] = {0.f, 0.f, 0.f, 0.f};

  for (int c = 0; c <= qt; ++c) {
    __syncthreads();                       // protect LDS overwrite
    {
      // ---- stage K (hi/lo) row-major + V transposed; bf16; XOR-swizzle ----
      const int key = tid & 63, dg = tid >> 6;
      const float* kp = base + (size_t)(c * 64 + key) * N_QKV + C_DIM + (h << 6) + dg * 16;
      const float4 k0 = *(const float4*)(kp + 0);
      const float4 k1 = *(const float4*)(kp + 4);
      const float4 k2 = *(const float4*)(kp + 8);
      const float4 k3 = *(const float4*)(kp + 12);
      const float4 v0 = *(const float4*)(kp + C_DIM + 0);
      const float4 v1 = *(const float4*)(kp + C_DIM + 4);
      const float4 v2 = *(const float4*)(kp + C_DIM + 8);
      const float4 v3 = *(const float4*)(kp + C_DIM + 12);
      const float kv[16] = {k0.x,k0.y,k0.z,k0.w, k1.x,k1.y,k1.z,k1.w,
                            k2.x,k2.y,k2.z,k2.w, k3.x,k3.y,k3.z,k3.w};
      const float vv[16] = {v0.x,v0.y,v0.z,v0.w, v1.x,v1.y,v1.z,v1.w,
                            v2.x,v2.y,v2.z,v2.w, v3.x,v3.y,v3.z,v3.w};
      short8 khi0, khi1, klo0, klo1;
#pragma unroll
      for (int j = 0; j < 8; ++j) {
        const float x0 = kv[j], x1 = kv[8 + j];
        const unsigned short h0 = f2bf(x0), h1 = f2bf(x1);
        khi0[j] = (short)h0; khi1[j] = (short)h1;
        klo0[j] = (short)f2bf(x0 - bf2f(h0));
        klo1[j] = (short)f2bf(x1 - bf2f(h1));
      }
      const int sw = (key & 7) << 4;
      const int b0 = key * 128 + ((dg * 32) ^ sw);
      const int b1 = key * 128 + ((dg * 32 + 16) ^ sw);
      *(short8*)(khp + b0) = khi0; *(short8*)(khp + b1) = khi1;
      *(short8*)(klp + b0) = klo0; *(short8*)(klp + b1) = klo1;
#pragma unroll
      for (int i = 0; i < 16; ++i) {
        const int d = dg * 16 + i;
        const int vb = d * 128 + ((key * 2) ^ ((i & 7) << 4));
        *(short*)(vTp + vb) = (short)f2bf(vv[i]);
      }
    }
    __syncthreads();

    // ---- QK^T: 3-pass split MFMA -> fp32-accurate scores ----
    f32x4 s4[4] = {{0.f,0.f,0.f,0.f},{0.f,0.f,0.f,0.f},{0.f,0.f,0.f,0.f},{0.f,0.f,0.f,0.f}};
#pragma unroll
    for (int s = 0; s < 2; ++s) {
      const int cb = s * 64 + lg * 16;     // byte col of my 8 bf16
#pragma unroll
      for (int f = 0; f < 4; ++f) {
        const int row = lr + 16 * f;       // key row
        const int byt = row * 128 + (cb ^ ((row & 7) << 4));
        const short8 bh = *(const short8*)(khp + byt);
        const short8 bl = *(const short8*)(klp + byt);
        s4[f] = __builtin_amdgcn_mfma_f32_16x16x32_bf16(qh[s], bh, s4[f], 0, 0, 0);
        s4[f] = __builtin_amdgcn_mfma_f32_16x16x32_bf16(ql[s], bh, s4[f], 0, 0, 0);
        s4[f] = __builtin_amdgcn_mfma_f32_16x16x32_bf16(qh[s], bl, s4[f], 0, 0, 0);
      }
    }

    if (c == qt) {                          // diagonal chunk: causal mask
#pragma unroll
      for (int f = 0; f < 4; ++f) {
        const int kg = 16 * f + lr;         // key within tile
#pragma unroll
        for (int r = 0; r < 4; ++r) {
          const int qg = w * 16 + lg * 4 + r;  // query within tile
          if (kg > qg) s4[f][r] = -1e30f;
        }
      }
    }

    // ---- online softmax (row state replicated across the 16 lanes of a row) ----
    float mc[4], resc[4], ps[4];
#pragma unroll
    for (int r = 0; r < 4; ++r)
      mc[r] = fmaxf(fmaxf(s4[0][r], s4[1][r]), fmaxf(s4[2][r], s4[3][r]));
#pragma unroll
    for (int d = 1; d <= 8; d <<= 1)
#pragma unroll
      for (int r = 0; r < 4; ++r) mc[r] = fmaxf(mc[r], __shfl_xor(mc[r], d));
#pragma unroll
    for (int r = 0; r < 4; ++r) {
      const float mn = fmaxf(m[r], mc[r]);
      resc[r] = __expf(m[r] - mn);
      m[r] = mn;
      ps[r] = 0.f;
    }
#pragma unroll
    for (int f = 0; f < 4; ++f)
#pragma unroll
      for (int r = 0; r < 4; ++r) {
        const float p = __expf(s4[f][r] - m[r]);
        s4[f][r] = p;
        ps[r] += p;
      }
#pragma unroll
    for (int d = 1; d <= 8; d <<= 1)
#pragma unroll
      for (int r = 0; r < 4; ++r) ps[r] += __shfl_xor(ps[r], d);
#pragma unroll
    for (int r = 0; r < 4; ++r) lsum[r] = lsum[r] * resc[r] + ps[r];
#pragma unroll
    for (int n = 0; n < 4; ++n)
#pragma unroll
      for (int r = 0; r < 4; ++r) O[n][r] *= resc[r];

    // ---- P (D-layout) -> bf16 -> per-wave LDS (A-layout read) ----
#pragma unroll
    for (int f = 0; f < 4; ++f)
#pragma unroll
      for (int r = 0; r < 4; ++r) {
        const int q = lg * 4 + r;
        const int byt = (w << 11) + q * 128 + (((lr + 16 * f) * 2) ^ ((q & 7) << 4));
        *(short*)(pp + byt) = (short)f2bf(s4[f][r]);
      }

    // ---- PV: O += P * V ----
#pragma unroll
    for (int s = 0; s < 2; ++s) {
      const int cb = s * 64 + lg * 16;
      const short8 pa = *(const short8*)(pp + (w << 11) + lr * 128 + (cb ^ ((lr & 7) << 4)));
#pragma unroll
      for (int n = 0; n < 4; ++n) {
        const int d = lr + 16 * n;
        const short8 vb = *(const short8*)(vTp + d * 128 + (cb ^ ((d & 7) << 4)));
        O[n] = __builtin_amdgcn_mfma_f32_16x16x32_bf16(pa, vb, O[n], 0, 0, 0);
      }
    }
  }

  float inv[4];
#pragma unroll
  for (int r = 0; r < 4; ++r) inv[r] = 1.f / lsum[r];
  float* orow = aout + (size_t)(b * T_SEQ + qt * 64 + w * 16 + lg * 4) * C_DIM + (h << 6) + lr;
#pragma unroll
  for (int r = 0; r < 4; ++r)
#pragma unroll
    for (int n = 0; n < 4; ++n)
      orow[(size_t)r * C_DIM + 16 * n] = O[n][r] * inv[r];
}

// ---------------- launch ----------------------------------------------------
extern "C" void kernel_launch(void* const* d_in, const int* in_sizes, int n_in,
                              void* d_out, int out_size, void* d_ws, size_t ws_size,
                              hipStream_t stream) {
  const float* x      = (const float*)d_in[0];   // [4096][1024]
  const float* w_qkv  = (const float*)d_in[1];   // [3072][1024]
  const float* w_out  = (const float*)d_in[2];   // [1024][1024]
  float* out = (float*)d_out;                    // [4096][1024]
  float* ws = (float*)d_ws;

  float* wt_qkv = ws;
  float* wt_out = wt_qkv + (size_t)N_QKV * C_DIM;
  float* qkv    = wt_out + (size_t)C_DIM * C_DIM;
  float* aout   = qkv + (size_t)M_ROWS * N_QKV;
  float* part   = aout + (size_t)M_ROWS * C_DIM;
  float* scales = part + 512;

  hipLaunchKernelGGL(abs_partial_k, dim3(256), dim3(256), 0, stream,
                     w_qkv, N_QKV * C_DIM, part);
  hipLaunchKernelGGL(abs_partial_k, dim3(256), dim3(256), 0, stream,
                     w_out, C_DIM * C_DIM, part + 256);
  hipLaunchKernelGGL(finalize_scales_k, dim3(2), dim3(256), 0, stream, part, scales);

  hipLaunchKernelGGL(ternarize_k, dim3((N_QKV * C_DIM) / 256), dim3(256), 0, stream,
                     w_qkv, wt_qkv, N_QKV * C_DIM, scales, 0);
  hipLaunchKernelGGL(ternarize_k, dim3((C_DIM * C_DIM) / 256), dim3(256), 0, stream,
                     w_out, wt_out, C_DIM * C_DIM, scales, 1);

  hipLaunchKernelGGL(gemm_nt, dim3(N_QKV / 64, M_ROWS / 64), dim3(256), 0, stream,
                     x, wt_qkv, qkv, N_QKV, C_DIM);

  hipLaunchKernelGGL(attn_mfma_k, dim3(1024), dim3(256), 0, stream, qkv, aout);

  hipLaunchKernelGGL(gemm_nt, dim3(C_DIM / 64, M_ROWS / 64), dim3(256), 0, stream,
                     aout, wt_out, out, C_DIM, C_DIM);
}

// Round 4
// 275.449 us; speedup vs baseline: 9.8588x; 2.2973x over previous
//
#include <hip/hip_runtime.h>
#include <math.h>

#define T_SEQ 2048
#define C_DIM 1024
#define NHEAD 16
#define HDIM 64
#define M_ROWS 4096   // B*T
#define N_QKV 3072    // 3*C

typedef __attribute__((ext_vector_type(8))) short short8;   // 8 bf16 (4 VGPR)
typedef __attribute__((ext_vector_type(4))) float f32x4;    // MFMA C/D
typedef unsigned short ushort_t;

__device__ inline unsigned short f2bf(float x) {            // RNE f32->bf16
  union { float f; unsigned u; } v; v.f = x;
  unsigned r = v.u + 0x7FFF + ((v.u >> 16) & 1);
  return (unsigned short)(r >> 16);
}
__device__ inline float bf2f(unsigned short h) {
  union { unsigned u; float f; } v; v.u = ((unsigned)h) << 16; return v.f;
}

// ---------------- abs-mean scale (deterministic 2-stage reduction) ----------
__global__ __launch_bounds__(256) void abs_partial_k(const float* __restrict__ w,
                                                     int n, float* __restrict__ part) {
  __shared__ float red[256];
  float s = 0.f;
  for (int i = blockIdx.x * 256 + threadIdx.x; i < n; i += 256 * 256)
    s += fabsf(w[i]);
  red[threadIdx.x] = s;
  __syncthreads();
  for (int st = 128; st > 0; st >>= 1) {
    if ((int)threadIdx.x < st) red[threadIdx.x] += red[threadIdx.x + st];
    __syncthreads();
  }
  if (threadIdx.x == 0) part[blockIdx.x] = red[0];
}

__global__ __launch_bounds__(256) void finalize_scales_k(const float* __restrict__ part,
                                                         float* __restrict__ scales) {
  __shared__ float red[256];
  red[threadIdx.x] = part[blockIdx.x * 256 + threadIdx.x];
  __syncthreads();
  for (int st = 128; st > 0; st >>= 1) {
    if ((int)threadIdx.x < st) red[threadIdx.x] += red[threadIdx.x + st];
    __syncthreads();
  }
  if (threadIdx.x == 0) {
    float n = (blockIdx.x == 0) ? (float)(N_QKV * C_DIM) : (float)(C_DIM * C_DIM);
    scales[blockIdx.x] = fmaxf(red[0] / n, 1e-8f);
  }
}

// ---------------- ternarize -> bf16 (exact: {-1,0,1}) -----------------------
__global__ __launch_bounds__(256) void ternarize_k(const float* __restrict__ w,
                                                   ushort_t* __restrict__ wt, int n,
                                                   const float* __restrict__ scales,
                                                   int which) {
  int i = blockIdx.x * 256 + threadIdx.x;
  if (i < n) {
    float s = scales[which];
    float t = rintf(w[i] / s);           // round-half-even matches jnp.round
    wt[i] = f2bf(fminf(1.f, fmaxf(-1.f, t)));
  }
}

// ---------------- fp32 -> bf16 hi/lo split ----------------------------------
__global__ __launch_bounds__(256) void split_hl_k(const float* __restrict__ in,
                                                  ushort_t* __restrict__ hi,
                                                  ushort_t* __restrict__ lo, int n4) {
  int i = blockIdx.x * 256 + threadIdx.x;
  if (i < n4) {
    const float4 v = ((const float4*)in)[i];
    const float vv[4] = {v.x, v.y, v.z, v.w};
    ushort_t hh[4], ll[4];
#pragma unroll
    for (int j = 0; j < 4; ++j) {
      hh[j] = f2bf(vv[j]);
      ll[j] = f2bf(vv[j] - bf2f(hh[j]));
    }
    ((ushort4*)hi)[i] = make_ushort4(hh[0], hh[1], hh[2], hh[3]);
    ((ushort4*)lo)[i] = make_ushort4(ll[0], ll[1], ll[2], ll[3]);
  }
}

// ---------------- bf16 MFMA GEMM, A split hi/lo -----------------------------
// C[m][n] = sum_k (Ah+Al)[m][k] * Bw[n][k];  tile 128x128, BK=32, 4 waves 2x2.
__global__ __launch_bounds__(256) void gemm_bf16_hl(const ushort_t* __restrict__ Ah,
                                                    const ushort_t* __restrict__ Al,
                                                    const ushort_t* __restrict__ Bw,
                                                    float* __restrict__ C,
                                                    int Nd, int Kd) {
  __shared__ __align__(16) ushort_t Ash[128 * 32];
  __shared__ __align__(16) ushort_t Asl[128 * 32];
  __shared__ __align__(16) ushort_t Bs[128 * 32];
  const int tid = threadIdx.x;
  const int bm = blockIdx.y << 7, bn = blockIdx.x << 7;
  const int w = tid >> 6, lane = tid & 63;
  const int wm = (w >> 1) << 6, wn = (w & 1) << 6;
  const int fr = lane & 15, fc = lane >> 4;
  const int srow = tid >> 1;                 // staging row 0..127
  const int scol = (tid & 1) << 4;           // staging col 0 / 16

  const ushort_t* Aph = Ah + (size_t)(bm + srow) * Kd + scol;
  const ushort_t* Apl = Al + (size_t)(bm + srow) * Kd + scol;
  const ushort_t* Bp  = Bw + (size_t)(bn + srow) * Kd + scol;
  ushort_t* const sA = Ash + srow * 32 + scol;
  ushort_t* const sL = Asl + srow * 32 + scol;
  ushort_t* const sB = Bs  + srow * 32 + scol;

  f32x4 acc[4][4];
  const f32x4 z = {0.f, 0.f, 0.f, 0.f};
#pragma unroll
  for (int i = 0; i < 4; ++i)
#pragma unroll
    for (int j = 0; j < 4; ++j) acc[i][j] = z;

  for (int k0 = 0; k0 < Kd; k0 += 32) {
    const short8 a0 = *(const short8*)(Aph + k0);
    const short8 a1 = *(const short8*)(Aph + k0 + 8);
    const short8 l0 = *(const short8*)(Apl + k0);
    const short8 l1 = *(const short8*)(Apl + k0 + 8);
    const short8 b0 = *(const short8*)(Bp + k0);
    const short8 b1 = *(const short8*)(Bp + k0 + 8);
    __syncthreads();                        // previous compute done
    *(short8*)(sA) = a0; *(short8*)(sA + 8) = a1;
    *(short8*)(sL) = l0; *(short8*)(sL + 8) = l1;
    *(short8*)(sB) = b0; *(short8*)(sB + 8) = b1;
    __syncthreads();

    short8 af[4], lf[4], bf[4];
#pragma unroll
    for (int i = 0; i < 4; ++i) {
      af[i] = *(const short8*)(Ash + (wm + i * 16 + fr) * 32 + fc * 8);
      lf[i] = *(const short8*)(Asl + (wm + i * 16 + fr) * 32 + fc * 8);
      bf[i] = *(const short8*)(Bs  + (wn + i * 16 + fr) * 32 + fc * 8);
    }
#pragma unroll
    for (int i = 0; i < 4; ++i)
#pragma unroll
      for (int j = 0; j < 4; ++j) {
        acc[i][j] = __builtin_amdgcn_mfma_f32_16x16x32_bf16(af[i], bf[j], acc[i][j], 0, 0, 0);
        acc[i][j] = __builtin_amdgcn_mfma_f32_16x16x32_bf16(lf[i], bf[j], acc[i][j], 0, 0, 0);
      }
  }
#pragma unroll
  for (int i = 0; i < 4; ++i)
#pragma unroll
    for (int j = 0; j < 4; ++j) {
      float* cp = C + (size_t)(bm + wm + i * 16 + fc * 4) * Nd + bn + wn + j * 16 + fr;
#pragma unroll
      for (int r = 0; r < 4; ++r) cp[(size_t)r * Nd] = acc[i][j][r];
    }
}

// ---------------- MFMA flash attention (emits bf16 hi/lo) -------------------
__global__ __launch_bounds__(256, 2) void attn_mfma_k(const float* __restrict__ qkv,
                                                      ushort_t* __restrict__ oh,
                                                      ushort_t* __restrict__ ol) {
  __shared__ __align__(16) char smem[32768];
  char* const khp = smem;            // K hi  [64 key][64 dim] bf16, swizzled
  char* const klp = smem + 8192;     // K lo
  char* const vTp = smem + 16384;    // V^T  [64 dim][64 key] bf16, swizzled
  char* const pp  = smem + 24576;    // P    per-wave [16 q][64 key] bf16

  const int tid  = threadIdx.x;
  const int lane = tid & 63;
  const int w    = tid >> 6;
  const int lg   = lane >> 4;
  const int lr   = lane & 15;

  const int bx = blockIdx.x;
  const int qt = (bx >> 3) & 31;
  const int gg = ((bx >> 8) << 3) | (bx & 7);
  const int h  = gg & 15, b = gg >> 4;

  const float* base = qkv + (size_t)b * T_SEQ * N_QKV;

  short8 qh[2], ql[2];
  {
    const float* qrow = base + (size_t)(qt * 64 + w * 16 + lr) * N_QKV + (h << 6);
#pragma unroll
    for (int s = 0; s < 2; ++s) {
      const float4 a0 = *(const float4*)(qrow + s * 32 + lg * 8);
      const float4 a1 = *(const float4*)(qrow + s * 32 + lg * 8 + 4);
      const float xv[8] = {a0.x, a0.y, a0.z, a0.w, a1.x, a1.y, a1.z, a1.w};
#pragma unroll
      for (int j = 0; j < 8; ++j) {
        const float xs = xv[j] * 0.125f;
        const unsigned short hs = f2bf(xs);
        qh[s][j] = (short)hs;
        ql[s][j] = (short)f2bf(xs - bf2f(hs));
      }
    }
  }

  f32x4 O[4] = {{0.f,0.f,0.f,0.f},{0.f,0.f,0.f,0.f},{0.f,0.f,0.f,0.f},{0.f,0.f,0.f,0.f}};
  float m[4]    = {-1e30f, -1e30f, -1e30f, -1e30f};
  float lsum[4] = {0.f, 0.f, 0.f, 0.f};

  for (int c = 0; c <= qt; ++c) {
    __syncthreads();
    {
      const int key = tid & 63, dg = tid >> 6;
      const float* kp = base + (size_t)(c * 64 + key) * N_QKV + C_DIM + (h << 6) + dg * 16;
      const float4 k0 = *(const float4*)(kp + 0);
      const float4 k1 = *(const float4*)(kp + 4);
      const float4 k2 = *(const float4*)(kp + 8);
      const float4 k3 = *(const float4*)(kp + 12);
      const float4 v0 = *(const float4*)(kp + C_DIM + 0);
      const float4 v1 = *(const float4*)(kp + C_DIM + 4);
      const float4 v2 = *(const float4*)(kp + C_DIM + 8);
      const float4 v3 = *(const float4*)(kp + C_DIM + 12);
      const float kv[16] = {k0.x,k0.y,k0.z,k0.w, k1.x,k1.y,k1.z,k1.w,
                            k2.x,k2.y,k2.z,k2.w, k3.x,k3.y,k3.z,k3.w};
      const float vv[16] = {v0.x,v0.y,v0.z,v0.w, v1.x,v1.y,v1.z,v1.w,
                            v2.x,v2.y,v2.z,v2.w, v3.x,v3.y,v3.z,v3.w};
      short8 khi0, khi1, klo0, klo1;
#pragma unroll
      for (int j = 0; j < 8; ++j) {
        const float x0 = kv[j], x1 = kv[8 + j];
        const unsigned short h0 = f2bf(x0), h1 = f2bf(x1);
        khi0[j] = (short)h0; khi1[j] = (short)h1;
        klo0[j] = (short)f2bf(x0 - bf2f(h0));
        klo1[j] = (short)f2bf(x1 - bf2f(h1));
      }
      const int sw = (key & 7) << 4;
      const int b0 = key * 128 + ((dg * 32) ^ sw);
      const int b1 = key * 128 + ((dg * 32 + 16) ^ sw);
      *(short8*)(khp + b0) = khi0; *(short8*)(khp + b1) = khi1;
      *(short8*)(klp + b0) = klo0; *(short8*)(klp + b1) = klo1;
#pragma unroll
      for (int i = 0; i < 16; ++i) {
        const int d = dg * 16 + i;
        const int vb = d * 128 + ((key * 2) ^ ((i & 7) << 4));
        *(short*)(vTp + vb) = (short)f2bf(vv[i]);
      }
    }
    __syncthreads();

    f32x4 s4[4] = {{0.f,0.f,0.f,0.f},{0.f,0.f,0.f,0.f},{0.f,0.f,0.f,0.f},{0.f,0.f,0.f,0.f}};
#pragma unroll
    for (int s = 0; s < 2; ++s) {
      const int cb = s * 64 + lg * 16;
#pragma unroll
      for (int f = 0; f < 4; ++f) {
        const int row = lr + 16 * f;
        const int byt = row * 128 + (cb ^ ((row & 7) << 4));
        const short8 bh = *(const short8*)(khp + byt);
        const short8 bl = *(const short8*)(klp + byt);
        s4[f] = __builtin_amdgcn_mfma_f32_16x16x32_bf16(qh[s], bh, s4[f], 0, 0, 0);
        s4[f] = __builtin_amdgcn_mfma_f32_16x16x32_bf16(ql[s], bh, s4[f], 0, 0, 0);
        s4[f] = __builtin_amdgcn_mfma_f32_16x16x32_bf16(qh[s], bl, s4[f], 0, 0, 0);
      }
    }

    if (c == qt) {
#pragma unroll
      for (int f = 0; f < 4; ++f) {
        const int kg = 16 * f + lr;
#pragma unroll
        for (int r = 0; r < 4; ++r) {
          const int qg = w * 16 + lg * 4 + r;
          if (kg > qg) s4[f][r] = -1e30f;
        }
      }
    }

    float mc[4], resc[4], ps[4];
#pragma unroll
    for (int r = 0; r < 4; ++r)
      mc[r] = fmaxf(fmaxf(s4[0][r], s4[1][r]), fmaxf(s4[2][r], s4[3][r]));
#pragma unroll
    for (int d = 1; d <= 8; d <<= 1)
#pragma unroll
      for (int r = 0; r < 4; ++r) mc[r] = fmaxf(mc[r], __shfl_xor(mc[r], d));
#pragma unroll
    for (int r = 0; r < 4; ++r) {
      const float mn = fmaxf(m[r], mc[r]);
      resc[r] = __expf(m[r] - mn);
      m[r] = mn;
      ps[r] = 0.f;
    }
#pragma unroll
    for (int f = 0; f < 4; ++f)
#pragma unroll
      for (int r = 0; r < 4; ++r) {
        const float p = __expf(s4[f][r] - m[r]);
        s4[f][r] = p;
        ps[r] += p;
      }
#pragma unroll
    for (int d = 1; d <= 8; d <<= 1)
#pragma unroll
      for (int r = 0; r < 4; ++r) ps[r] += __shfl_xor(ps[r], d);
#pragma unroll
    for (int r = 0; r < 4; ++r) lsum[r] = lsum[r] * resc[r] + ps[r];
#pragma unroll
    for (int n = 0; n < 4; ++n)
#pragma unroll
      for (int r = 0; r < 4; ++r) O[n][r] *= resc[r];

#pragma unroll
    for (int f = 0; f < 4; ++f)
#pragma unroll
      for (int r = 0; r < 4; ++r) {
        const int q = lg * 4 + r;
        const int byt = (w << 11) + q * 128 + (((lr + 16 * f) * 2) ^ ((q & 7) << 4));
        *(short*)(pp + byt) = (short)f2bf(s4[f][r]);
      }

#pragma unroll
    for (int s = 0; s < 2; ++s) {
      const int cb = s * 64 + lg * 16;
      const short8 pa = *(const short8*)(pp + (w << 11) + lr * 128 + (cb ^ ((lr & 7) << 4)));
#pragma unroll
      for (int n = 0; n < 4; ++n) {
        const int d = lr + 16 * n;
        const short8 vb = *(const short8*)(vTp + d * 128 + (cb ^ ((d & 7) << 4)));
        O[n] = __builtin_amdgcn_mfma_f32_16x16x32_bf16(pa, vb, O[n], 0, 0, 0);
      }
    }
  }

  float inv[4];
#pragma unroll
  for (int r = 0; r < 4; ++r) inv[r] = 1.f / lsum[r];
  const size_t obase = (size_t)(b * T_SEQ + qt * 64 + w * 16 + lg * 4) * C_DIM + (h << 6) + lr;
#pragma unroll
  for (int r = 0; r < 4; ++r)
#pragma unroll
    for (int n = 0; n < 4; ++n) {
      const float val = O[n][r] * inv[r];
      const unsigned short hh = f2bf(val);
      oh[obase + (size_t)r * C_DIM + 16 * n] = hh;
      ol[obase + (size_t)r * C_DIM + 16 * n] = f2bf(val - bf2f(hh));
    }
}

// ---------------- launch ----------------------------------------------------
extern "C" void kernel_launch(void* const* d_in, const int* in_sizes, int n_in,
                              void* d_out, int out_size, void* d_ws, size_t ws_size,
                              hipStream_t stream) {
  const float* x      = (const float*)d_in[0];   // [4096][1024]
  const float* w_qkv  = (const float*)d_in[1];   // [3072][1024]
  const float* w_out  = (const float*)d_in[2];   // [1024][1024]
  float* out = (float*)d_out;                    // [4096][1024]

  char* p = (char*)d_ws;
  ushort_t* wt_qkv = (ushort_t*)p;  p += (size_t)N_QKV * C_DIM * 2;
  ushort_t* wt_out = (ushort_t*)p;  p += (size_t)C_DIM * C_DIM * 2;
  ushort_t* xh     = (ushort_t*)p;  p += (size_t)M_ROWS * C_DIM * 2;
  ushort_t* xl     = (ushort_t*)p;  p += (size_t)M_ROWS * C_DIM * 2;
  float*    qkv    = (float*)p;     p += (size_t)M_ROWS * N_QKV * 4;
  float*    part   = (float*)p;     p += 512 * 4;
  float*    scales = (float*)p;
  ushort_t* ah = xh;   // x hi/lo dead after gemm1 -> reuse for attn output
  ushort_t* al = xl;

  hipLaunchKernelGGL(abs_partial_k, dim3(256), dim3(256), 0, stream,
                     w_qkv, N_QKV * C_DIM, part);
  hipLaunchKernelGGL(abs_partial_k, dim3(256), dim3(256), 0, stream,
                     w_out, C_DIM * C_DIM, part + 256);
  hipLaunchKernelGGL(finalize_scales_k, dim3(2), dim3(256), 0, stream, part, scales);

  hipLaunchKernelGGL(ternarize_k, dim3((N_QKV * C_DIM) / 256), dim3(256), 0, stream,
                     w_qkv, wt_qkv, N_QKV * C_DIM, scales, 0);
  hipLaunchKernelGGL(ternarize_k, dim3((C_DIM * C_DIM) / 256), dim3(256), 0, stream,
                     w_out, wt_out, C_DIM * C_DIM, scales, 1);

  hipLaunchKernelGGL(split_hl_k, dim3((M_ROWS * C_DIM / 4) / 256), dim3(256), 0, stream,
                     x, xh, xl, M_ROWS * C_DIM / 4);

  // qkv = (xh+xl) @ wt_qkv^T
  hipLaunchKernelGGL(gemm_bf16_hl, dim3(N_QKV / 128, M_ROWS / 128), dim3(256), 0, stream,
                     xh, xl, wt_qkv, qkv, N_QKV, C_DIM);

  // attention -> bf16 hi/lo
  hipLaunchKernelGGL(attn_mfma_k, dim3(1024), dim3(256), 0, stream, qkv, ah, al);

  // out = (ah+al) @ wt_out^T
  hipLaunchKernelGGL(gemm_bf16_hl, dim3(C_DIM / 128, M_ROWS / 128), dim3(256), 0, stream,
                     ah, al, wt_out, out, C_DIM, C_DIM);
}

// Round 5
// 233.636 us; speedup vs baseline: 11.6232x; 1.1790x over previous
//
#include <hip/hip_runtime.h>
#include <math.h>

#define T_SEQ 2048
#define C_DIM 1024
#define NHEAD 16
#define HDIM 64
#define M_ROWS 4096   // B*T
#define N_QKV 3072    // 3*C

typedef __attribute__((ext_vector_type(8))) short short8;   // 8 bf16 (4 VGPR)
typedef __attribute__((ext_vector_type(4))) float f32x4;    // MFMA C/D
typedef unsigned short ushort_t;

__device__ inline unsigned short f2bf(float x) {            // RNE f32->bf16
  union { float f; unsigned u; } v; v.f = x;
  unsigned r = v.u + 0x7FFF + ((v.u >> 16) & 1);
  return (unsigned short)(r >> 16);
}
__device__ inline float bf2f(unsigned short h) {
  union { unsigned u; float f; } v; v.u = ((unsigned)h) << 16; return v.f;
}

// async global->LDS, 16B per lane; LDS dest = wave-uniform base + lane*16
__device__ __forceinline__ void gll16(const char* g, char* l) {
  __builtin_amdgcn_global_load_lds(
      (const __attribute__((address_space(1))) unsigned*)g,
      (__attribute__((address_space(3))) unsigned*)l, 16, 0, 0);
}

// ---------------- abs-mean scale (deterministic 2-stage reduction) ----------
__global__ __launch_bounds__(256) void abs_partial_k(const float* __restrict__ w,
                                                     int n, float* __restrict__ part) {
  __shared__ float red[256];
  float s = 0.f;
  for (int i = blockIdx.x * 256 + threadIdx.x; i < n; i += 256 * 256)
    s += fabsf(w[i]);
  red[threadIdx.x] = s;
  __syncthreads();
  for (int st = 128; st > 0; st >>= 1) {
    if ((int)threadIdx.x < st) red[threadIdx.x] += red[threadIdx.x + st];
    __syncthreads();
  }
  if (threadIdx.x == 0) part[blockIdx.x] = red[0];
}

__global__ __launch_bounds__(256) void finalize_scales_k(const float* __restrict__ part,
                                                         float* __restrict__ scales) {
  __shared__ float red[256];
  red[threadIdx.x] = part[blockIdx.x * 256 + threadIdx.x];
  __syncthreads();
  for (int st = 128; st > 0; st >>= 1) {
    if ((int)threadIdx.x < st) red[threadIdx.x] += red[threadIdx.x + st];
    __syncthreads();
  }
  if (threadIdx.x == 0) {
    float n = (blockIdx.x == 0) ? (float)(N_QKV * C_DIM) : (float)(C_DIM * C_DIM);
    scales[blockIdx.x] = fmaxf(red[0] / n, 1e-8f);
  }
}

// ---------------- ternarize -> bf16 (exact: {-1,0,1}) -----------------------
__global__ __launch_bounds__(256) void ternarize_k(const float* __restrict__ w,
                                                   ushort_t* __restrict__ wt, int n,
                                                   const float* __restrict__ scales,
                                                   int which) {
  int i = blockIdx.x * 256 + threadIdx.x;
  if (i < n) {
    float s = scales[which];
    float t = rintf(w[i] / s);           // round-half-even matches jnp.round
    wt[i] = f2bf(fminf(1.f, fmaxf(-1.f, t)));
  }
}

// ---------------- fp32 -> bf16 hi/lo split ----------------------------------
__global__ __launch_bounds__(256) void split_hl_k(const float* __restrict__ in,
                                                  ushort_t* __restrict__ hi,
                                                  ushort_t* __restrict__ lo, int n4) {
  int i = blockIdx.x * 256 + threadIdx.x;
  if (i < n4) {
    const float4 v = ((const float4*)in)[i];
    const float vv[4] = {v.x, v.y, v.z, v.w};
    ushort_t hh[4], ll[4];
#pragma unroll
    for (int j = 0; j < 4; ++j) {
      hh[j] = f2bf(vv[j]);
      ll[j] = f2bf(vv[j] - bf2f(hh[j]));
    }
    ((ushort4*)hi)[i] = make_ushort4(hh[0], hh[1], hh[2], hh[3]);
    ((ushort4*)lo)[i] = make_ushort4(ll[0], ll[1], ll[2], ll[3]);
  }
}

// ---------------- bf16 MFMA GEMM, A split hi/lo -----------------------------
// C[m][n] = sum_k (Ah+Al)[m][k] * Bw[n][k]; tile 128x128, BK=64, 4 waves 2x2.
// LDS rows 128B, XOR-swizzled (T2) -> conflict-free ds_read_b128.
__global__ __launch_bounds__(256) void gemm_bf16_hl(const ushort_t* __restrict__ Ah,
                                                    const ushort_t* __restrict__ Al,
                                                    const ushort_t* __restrict__ Bw,
                                                    float* __restrict__ C,
                                                    int Nd, int Kd) {
  __shared__ __align__(16) ushort_t Ash[128 * 64];
  __shared__ __align__(16) ushort_t Asl[128 * 64];
  __shared__ __align__(16) ushort_t Bs[128 * 64];
  const int tid = threadIdx.x;
  const int bm = blockIdx.y << 7, bn = blockIdx.x << 7;
  const int w = tid >> 6, lane = tid & 63;
  const int wm = (w >> 1) << 6, wn = (w & 1) << 6;
  const int fr = lane & 15, fc = lane >> 4;
  const int srow = tid >> 1;                 // staging row 0..127
  const int sv0 = (tid & 1) << 2;            // 16B-slot base: 0 or 4
  const int swz = (srow & 7) << 4;
  const size_t arow = (size_t)(bm + srow) * Kd;
  const size_t brow = (size_t)(bn + srow) * Kd;
  int wb[4];
#pragma unroll
  for (int j = 0; j < 4; ++j) wb[j] = srow * 128 + (((sv0 + j) << 4) ^ swz);

  f32x4 acc[4][4];
  const f32x4 z = {0.f, 0.f, 0.f, 0.f};
#pragma unroll
  for (int i = 0; i < 4; ++i)
#pragma unroll
    for (int j = 0; j < 4; ++j) acc[i][j] = z;

  for (int k0 = 0; k0 < Kd; k0 += 64) {
    const int gcol = k0 + (sv0 << 3);        // elem col: k0 + (tid&1)*32
    short8 sa[4], sl[4], sb[4];
#pragma unroll
    for (int j = 0; j < 4; ++j) {
      sa[j] = *(const short8*)(Ah + arow + gcol + j * 8);
      sl[j] = *(const short8*)(Al + arow + gcol + j * 8);
      sb[j] = *(const short8*)(Bw + brow + gcol + j * 8);
    }
    __syncthreads();
#pragma unroll
    for (int j = 0; j < 4; ++j) {
      *(short8*)((char*)Ash + wb[j]) = sa[j];
      *(short8*)((char*)Asl + wb[j]) = sl[j];
      *(short8*)((char*)Bs  + wb[j]) = sb[j];
    }
    __syncthreads();
#pragma unroll
    for (int ks = 0; ks < 2; ++ks) {
      short8 af[4], lf[4], bf[4];
#pragma unroll
      for (int i = 0; i < 4; ++i) {
        const int ra = wm + i * 16 + fr;
        af[i] = *(const short8*)((const char*)Ash + ra * 128 + ((ks * 64 + fc * 16) ^ ((ra & 7) << 4)));
        lf[i] = *(const short8*)((const char*)Asl + ra * 128 + ((ks * 64 + fc * 16) ^ ((ra & 7) << 4)));
        const int rb = wn + i * 16 + fr;
        bf[i] = *(const short8*)((const char*)Bs + rb * 128 + ((ks * 64 + fc * 16) ^ ((rb & 7) << 4)));
      }
#pragma unroll
      for (int i = 0; i < 4; ++i)
#pragma unroll
        for (int j = 0; j < 4; ++j) {
          acc[i][j] = __builtin_amdgcn_mfma_f32_16x16x32_bf16(af[i], bf[j], acc[i][j], 0, 0, 0);
          acc[i][j] = __builtin_amdgcn_mfma_f32_16x16x32_bf16(lf[i], bf[j], acc[i][j], 0, 0, 0);
        }
    }
  }
#pragma unroll
  for (int i = 0; i < 4; ++i)
#pragma unroll
    for (int j = 0; j < 4; ++j) {
      float* cp = C + (size_t)(bm + wm + i * 16 + fc * 4) * Nd + bn + wn + j * 16 + fr;
#pragma unroll
      for (int r = 0; r < 4; ++r) cp[(size_t)r * Nd] = acc[i][j][r];
    }
}

// ---------------- prep_kv: per-(b,h,chunk) swizzled LDS images --------------
// Image 24KB = [khi 8KB | klo 8KB | vT 8KB], exactly the bytes attn wants.
__global__ __launch_bounds__(256) void prep_kv_k(const float* __restrict__ qkv,
                                                 char* __restrict__ img) {
  __shared__ __align__(16) char sm[24576];
  const int tid = threadIdx.x;
  const int c = blockIdx.x & 31, gg = blockIdx.x >> 5;
  const int h = gg & 15, b = gg >> 4;
  const int key = tid >> 2, dg = tid & 3;    // 4 threads per key row (coalesced)
  const float* kp = qkv + (size_t)b * T_SEQ * N_QKV +
                    (size_t)(c * 64 + key) * N_QKV + C_DIM + (h << 6) + dg * 16;
  const float4 k0 = *(const float4*)(kp + 0);
  const float4 k1 = *(const float4*)(kp + 4);
  const float4 k2 = *(const float4*)(kp + 8);
  const float4 k3 = *(const float4*)(kp + 12);
  const float4 v0 = *(const float4*)(kp + C_DIM + 0);
  const float4 v1 = *(const float4*)(kp + C_DIM + 4);
  const float4 v2 = *(const float4*)(kp + C_DIM + 8);
  const float4 v3 = *(const float4*)(kp + C_DIM + 12);
  const float kv[16] = {k0.x,k0.y,k0.z,k0.w, k1.x,k1.y,k1.z,k1.w,
                        k2.x,k2.y,k2.z,k2.w, k3.x,k3.y,k3.z,k3.w};
  const float vv[16] = {v0.x,v0.y,v0.z,v0.w, v1.x,v1.y,v1.z,v1.w,
                        v2.x,v2.y,v2.z,v2.w, v3.x,v3.y,v3.z,v3.w};
  short8 khi0, khi1, klo0, klo1;
#pragma unroll
  for (int j = 0; j < 8; ++j) {
    const float x0 = kv[j], x1 = kv[8 + j];
    const unsigned short h0 = f2bf(x0), h1 = f2bf(x1);
    khi0[j] = (short)h0; khi1[j] = (short)h1;
    klo0[j] = (short)f2bf(x0 - bf2f(h0));
    klo1[j] = (short)f2bf(x1 - bf2f(h1));
  }
  const int sw = (key & 7) << 4;
  const int b0 = key * 128 + ((dg * 32) ^ sw);
  const int b1 = key * 128 + ((dg * 32 + 16) ^ sw);
  *(short8*)(sm + b0) = khi0;        *(short8*)(sm + b1) = khi1;
  *(short8*)(sm + 8192 + b0) = klo0; *(short8*)(sm + 8192 + b1) = klo1;
#pragma unroll
  for (int i = 0; i < 16; ++i) {
    const int d = dg * 16 + i;
    *(short*)(sm + 16384 + d * 128 + ((key * 2) ^ ((d & 7) << 4))) = (short)f2bf(vv[i]);
  }
  __syncthreads();
  int4* dst = (int4*)(img + (size_t)blockIdx.x * 24576);
  const int4* src = (const int4*)sm;
#pragma unroll
  for (int i = 0; i < 6; ++i) dst[i * 256 + tid] = src[i * 256 + tid];
}

// ---------------- paired-tile MFMA flash attention --------------------------
// Block = (pair p, (b,h)); q-tiles qtA=p, qtB=31-p share one chunk loop ->
// exactly 33 tile-computes per block. Double-buffered 24KB chunk images via
// global_load_lds; one barrier per chunk.
struct TS { f32x4 O[4]; float m[4]; float l[4]; };

__device__ __forceinline__ void tile_step(const char* khp, const char* klp,
                                          const char* vTp, char* pp,
                                          const short8* qh, const short8* ql,
                                          TS& st, const bool diag,
                                          const int w, const int lg, const int lr) {
  f32x4 s4[4];
  const f32x4 z = {0.f, 0.f, 0.f, 0.f};
#pragma unroll
  for (int f = 0; f < 4; ++f) s4[f] = z;
#pragma unroll
  for (int s = 0; s < 2; ++s) {
    const int cb = s * 64 + lg * 16;
#pragma unroll
    for (int f = 0; f < 4; ++f) {
      const int row = lr + 16 * f;
      const int byt = row * 128 + (cb ^ ((row & 7) << 4));
      const short8 bh8 = *(const short8*)(khp + byt);
      const short8 bl8 = *(const short8*)(klp + byt);
      s4[f] = __builtin_amdgcn_mfma_f32_16x16x32_bf16(qh[s], bh8, s4[f], 0, 0, 0);
      s4[f] = __builtin_amdgcn_mfma_f32_16x16x32_bf16(ql[s], bh8, s4[f], 0, 0, 0);
      s4[f] = __builtin_amdgcn_mfma_f32_16x16x32_bf16(qh[s], bl8, s4[f], 0, 0, 0);
    }
  }
  if (diag) {
#pragma unroll
    for (int f = 0; f < 4; ++f) {
      const int kg = 16 * f + lr;
#pragma unroll
      for (int r = 0; r < 4; ++r) {
        const int qg = w * 16 + lg * 4 + r;
        if (kg > qg) s4[f][r] = -1e30f;
      }
    }
  }
  float mc[4], resc[4], ps[4];
#pragma unroll
  for (int r = 0; r < 4; ++r)
    mc[r] = fmaxf(fmaxf(s4[0][r], s4[1][r]), fmaxf(s4[2][r], s4[3][r]));
#pragma unroll
  for (int d = 1; d <= 8; d <<= 1)
#pragma unroll
    for (int r = 0; r < 4; ++r) mc[r] = fmaxf(mc[r], __shfl_xor(mc[r], d));
#pragma unroll
  for (int r = 0; r < 4; ++r) {
    const float mn = fmaxf(st.m[r], mc[r]);
    resc[r] = __expf(st.m[r] - mn);
    st.m[r] = mn;
    ps[r] = 0.f;
  }
#pragma unroll
  for (int f = 0; f < 4; ++f)
#pragma unroll
    for (int r = 0; r < 4; ++r) {
      const float p = __expf(s4[f][r] - st.m[r]);
      s4[f][r] = p;
      ps[r] += p;
    }
#pragma unroll
  for (int d = 1; d <= 8; d <<= 1)
#pragma unroll
    for (int r = 0; r < 4; ++r) ps[r] += __shfl_xor(ps[r], d);
#pragma unroll
  for (int r = 0; r < 4; ++r) st.l[r] = st.l[r] * resc[r] + ps[r];
#pragma unroll
  for (int n = 0; n < 4; ++n)
#pragma unroll
    for (int r = 0; r < 4; ++r) st.O[n][r] *= resc[r];
#pragma unroll
  for (int f = 0; f < 4; ++f)
#pragma unroll
    for (int r = 0; r < 4; ++r) {
      const int q = lg * 4 + r;
      *(short*)(pp + q * 128 + (((lr + 16 * f) * 2) ^ ((q & 7) << 4))) = (short)f2bf(s4[f][r]);
    }
#pragma unroll
  for (int s = 0; s < 2; ++s) {
    const int cb = s * 64 + lg * 16;
    const short8 pa = *(const short8*)(pp + lr * 128 + (cb ^ ((lr & 7) << 4)));
#pragma unroll
    for (int n = 0; n < 4; ++n) {
      const int d = lr + 16 * n;
      const short8 vb = *(const short8*)(vTp + d * 128 + (cb ^ ((d & 7) << 4)));
      st.O[n] = __builtin_amdgcn_mfma_f32_16x16x32_bf16(pa, vb, st.O[n], 0, 0, 0);
    }
  }
}

__device__ __forceinline__ void load_q(const float* base, int qt, int h,
                                       int w, int lg, int lr,
                                       short8* qh, short8* ql) {
  const float* qrow = base + (size_t)(qt * 64 + w * 16 + lr) * N_QKV + (h << 6);
#pragma unroll
  for (int s = 0; s < 2; ++s) {
    const float4 a0 = *(const float4*)(qrow + s * 32 + lg * 8);
    const float4 a1 = *(const float4*)(qrow + s * 32 + lg * 8 + 4);
    const float xv[8] = {a0.x, a0.y, a0.z, a0.w, a1.x, a1.y, a1.z, a1.w};
#pragma unroll
    for (int j = 0; j < 8; ++j) {
      const float xs = xv[j] * 0.125f;       // fold 1/sqrt(64)
      const unsigned short hs = f2bf(xs);
      qh[s][j] = (short)hs;
      ql[s][j] = (short)f2bf(xs - bf2f(hs));
    }
  }
}

__device__ __forceinline__ void store_o(ushort_t* oh, ushort_t* ol, TS& st,
                                        int b, int qt, int h,
                                        int w, int lg, int lr) {
  float inv[4];
#pragma unroll
  for (int r = 0; r < 4; ++r) inv[r] = 1.f / st.l[r];
  const size_t ob = (size_t)(b * T_SEQ + qt * 64 + w * 16 + lg * 4) * C_DIM + (h << 6) + lr;
#pragma unroll
  for (int r = 0; r < 4; ++r)
#pragma unroll
    for (int n = 0; n < 4; ++n) {
      const float val = st.O[n][r] * inv[r];
      const unsigned short hh = f2bf(val);
      oh[ob + (size_t)r * C_DIM + 16 * n] = hh;
      ol[ob + (size_t)r * C_DIM + 16 * n] = f2bf(val - bf2f(hh));
    }
}

__global__ __launch_bounds__(256) void attn2_k(const float* __restrict__ qkv,
                                               const char* __restrict__ img,
                                               ushort_t* __restrict__ oh,
                                               ushort_t* __restrict__ ol) {
  __shared__ __align__(16) char smem[57344];   // buf0 24K | buf1 24K | P 4x2K
  const int tid  = threadIdx.x;
  const int lane = tid & 63;
  const int w    = tid >> 6;
  const int lg   = lane >> 4;
  const int lr   = lane & 15;
  char* const pp = smem + 49152 + (w << 11);

  // gg in low bits -> all 16 p-blocks of one (b,h) land on one XCD (L2-hot img)
  const int bx = blockIdx.x;
  const int p  = (bx >> 3) & 15;
  const int gg = ((bx >> 7) << 3) | (bx & 7);
  const int h  = gg & 15, b = gg >> 4;
  const int qtA = p, qtB = 31 - p;

  const float* base = qkv + (size_t)b * T_SEQ * N_QKV;
  const char* img_gg = img + (size_t)gg * 32 * 24576;

  short8 qhA[2], qlA[2], qhB[2], qlB[2];
  load_q(base, qtA, h, w, lg, lr, qhA, qlA);
  load_q(base, qtB, h, w, lg, lr, qhB, qlB);

  TS stA, stB;
#pragma unroll
  for (int n = 0; n < 4; ++n) {
    const f32x4 z = {0.f, 0.f, 0.f, 0.f};
    stA.O[n] = z; stB.O[n] = z;
    stA.m[n] = -1e30f; stB.m[n] = -1e30f;
    stA.l[n] = 0.f; stB.l[n] = 0.f;
  }

  // prologue: issue chunk 0 into buf0
#pragma unroll
  for (int i = 0; i < 6; ++i)
    gll16(img_gg + i * 4096 + tid * 16, smem + i * 4096 + tid * 16);

  int cur = 0;
  for (int c = 0; c <= qtB; ++c) {
    __syncthreads();                         // drains outstanding loads (vmcnt 0)
    if (c < qtB) {
      const char* src = img_gg + (size_t)(c + 1) * 24576;
      char* dst = smem + (cur ^ 1) * 24576;
#pragma unroll
      for (int i = 0; i < 6; ++i)
        gll16(src + i * 4096 + tid * 16, dst + i * 4096 + tid * 16);
    }
    const char* kh = smem + cur * 24576;
    tile_step(kh, kh + 8192, kh + 16384, pp, qhB, qlB, stB, c == qtB, w, lg, lr);
    if (c <= qtA)
      tile_step(kh, kh + 8192, kh + 16384, pp, qhA, qlA, stA, c == qtA, w, lg, lr);
    cur ^= 1;
  }

  store_o(oh, ol, stA, b, qtA, h, w, lg, lr);
  store_o(oh, ol, stB, b, qtB, h, w, lg, lr);
}

// ---------------- launch ----------------------------------------------------
extern "C" void kernel_launch(void* const* d_in, const int* in_sizes, int n_in,
                              void* d_out, int out_size, void* d_ws, size_t ws_size,
                              hipStream_t stream) {
  const float* x      = (const float*)d_in[0];   // [4096][1024]
  const float* w_qkv  = (const float*)d_in[1];   // [3072][1024]
  const float* w_out  = (const float*)d_in[2];   // [1024][1024]
  float* out = (float*)d_out;                    // [4096][1024]

  // layout (img aliases wt_qkv, which is dead after gemm1; stream-ordered)
  char* pch = (char*)d_ws;
  ushort_t* wt_out = (ushort_t*)pch;  pch += (size_t)C_DIM * C_DIM * 2;    // 2MB
  ushort_t* xh     = (ushort_t*)pch;  pch += (size_t)M_ROWS * C_DIM * 2;   // 8MB
  ushort_t* xl     = (ushort_t*)pch;  pch += (size_t)M_ROWS * C_DIM * 2;   // 8MB
  float*    qkv    = (float*)pch;     pch += (size_t)M_ROWS * N_QKV * 4;   // 48MB
  ushort_t* wt_qkv = (ushort_t*)pch;                                       // 6MB..
  char*     img    = pch;             pch += (size_t)1024 * 24576;         // 25.2MB
  float*    part   = (float*)pch;     pch += 512 * 4;
  float*    scales = (float*)pch;
  ushort_t* ah = xh;   // x hi/lo dead after gemm1 -> reuse for attn output
  ushort_t* al = xl;

  hipLaunchKernelGGL(abs_partial_k, dim3(256), dim3(256), 0, stream,
                     w_qkv, N_QKV * C_DIM, part);
  hipLaunchKernelGGL(abs_partial_k, dim3(256), dim3(256), 0, stream,
                     w_out, C_DIM * C_DIM, part + 256);
  hipLaunchKernelGGL(finalize_scales_k, dim3(2), dim3(256), 0, stream, part, scales);

  hipLaunchKernelGGL(ternarize_k, dim3((N_QKV * C_DIM) / 256), dim3(256), 0, stream,
                     w_qkv, wt_qkv, N_QKV * C_DIM, scales, 0);
  hipLaunchKernelGGL(ternarize_k, dim3((C_DIM * C_DIM) / 256), dim3(256), 0, stream,
                     w_out, wt_out, C_DIM * C_DIM, scales, 1);

  hipLaunchKernelGGL(split_hl_k, dim3((M_ROWS * C_DIM / 4) / 256), dim3(256), 0, stream,
                     x, xh, xl, M_ROWS * C_DIM / 4);

  // qkv = (xh+xl) @ wt_qkv^T
  hipLaunchKernelGGL(gemm_bf16_hl, dim3(N_QKV / 128, M_ROWS / 128), dim3(256), 0, stream,
                     xh, xl, wt_qkv, qkv, N_QKV, C_DIM);

  // K/V chunk images (overwrites wt_qkv region — dead now)
  hipLaunchKernelGGL(prep_kv_k, dim3(1024), dim3(256), 0, stream, qkv, img);

  // attention -> bf16 hi/lo
  hipLaunchKernelGGL(attn2_k, dim3(512), dim3(256), 0, stream, qkv, img, ah, al);

  // out = (ah+al) @ wt_out^T
  hipLaunchKernelGGL(gemm_bf16_hl, dim3(C_DIM / 128, M_ROWS / 128), dim3(256), 0, stream,
                     ah, al, wt_out, out, C_DIM, C_DIM);
}